// Round 9
// baseline (168.673 us; speedup 1.0000x reference)
//
#include <hip/hip_runtime.h>

#define LSEQ 1024
#define INDIM 256
#define DM 32
#define PD 64

typedef float f32x4 __attribute__((ext_vector_type(4)));

__device__ __forceinline__ void fma4(f32x4& a, float s, const f32x4& t) {
  a.x = fmaf(s, t.x, a.x); a.y = fmaf(s, t.y, a.y);
  a.z = fmaf(s, t.z, a.z); a.w = fmaf(s, t.w, a.w);
}

__device__ __forceinline__ void g2l16(const float* g, float* l) {
  __builtin_amdgcn_global_load_lds(
      (__attribute__((address_space(1))) void*)g,
      (__attribute__((address_space(3))) void*)l, 16, 0, 0);
}

// Fused prep, 4 rows per block (unchanged from R6):
template<bool WRT>
__global__ __launch_bounds__(256) void k_prep(const float* __restrict__ seq,
    const float* __restrict__ W1, const float* __restrict__ b1,
    const float* __restrict__ W2, float* __restrict__ sT,
    float* __restrict__ t_out) {
  int i0 = blockIdx.x * 4;
  int tid = threadIdx.x;
  __shared__ float srow[4][INDIM];
  __shared__ float part[4][2][DM];
  __shared__ float si[4][DM];
  ((f32x4*)&srow[0][0])[tid] =
      ((const f32x4*)(seq + (size_t)i0 * INDIM))[tid];
  __syncthreads();
  {
    int c = tid & 31, dseg = (tid >> 5) & 1, il = tid >> 6;
    float a = 0.f;
    #pragma unroll 16
    for (int d = 0; d < 128; ++d)
      a = fmaf(srow[il][dseg * 128 + d], W1[(dseg * 128 + d) * DM + c], a);
    part[il][dseg][c] = a;
  }
  __syncthreads();
  if (tid < 128) {
    int il = tid >> 5, c = tid & 31;
    float a = b1[c] + part[il][0][c] + part[il][1][c];
    si[il][c] = a;
    sT[c * LSEQ + i0 + il] = a;
  }
  __syncthreads();
  if constexpr (WRT) {
    int p = tid & 63, c0 = tid >> 6;
    #pragma unroll
    for (int k = 0; k < 8; ++k) {
      int c = c0 * 8 + k;
      float a0 = 0.f, a1 = 0.f, a2 = 0.f, a3 = 0.f;
      #pragma unroll
      for (int d = 0; d < DM; ++d) {
        float w = W2[(c * DM + d) * PD + p];
        a0 = fmaf(si[0][d], w, a0);
        a1 = fmaf(si[1][d], w, a1);
        a2 = fmaf(si[2][d], w, a2);
        a3 = fmaf(si[3][d], w, a3);
      }
      t_out[((size_t)(i0 + 0) * DM + c) * PD + p] = a0;
      t_out[((size_t)(i0 + 1) * DM + c) * PD + p] = a1;
      t_out[((size_t)(i0 + 2) * DM + c) * PD + p] = a2;
      t_out[((size_t)(i0 + 3) * DM + c) * PD + p] = a3;
    }
  }
}

// Barrier-free wave-pipelined main: 1024 blocks (one per i), 4 waves/block,
// each wave privately processes 256 j in 8 chunks of 32 j. Per chunk:
// ds_write s (per-wave slot) -> issue next s+pair loads -> compute -> store.
// No loop barriers; reads and writes stay concurrently in flight.
__global__ __launch_bounds__(256, 4) void k_mainw(const float* __restrict__ sT,
    const float* __restrict__ tg, const float* __restrict__ b2,
    const float* __restrict__ pair, float* __restrict__ out) {
  __shared__ float t_lds[DM * PD];            // 8 KB
  __shared__ float s_slot[4][2][32 * 32];     // 4 waves x 2 slots x 4 KB = 32 KB
  int tid = threadIdx.x;
  int lane = tid & 63, w = tid >> 6;
  // XCD-chunked bijective swizzle: XCD k owns i-band [k*128,(k+1)*128).
  int i = ((blockIdx.x & 7) << 7) + (blockIdx.x >> 3);
  int pl = lane & 7;      // p = pl*4..+3 and 32+pl*4..+3
  int q  = lane >> 3;     // j-quad within chunk: j = j0 + q*4 + jj

  // prologue: stage t[i] (only barrier in the kernel)
  {
    const float* tb = tg + (size_t)i * (DM * PD) + w * 512 + lane * 4;
    float* tl = t_lds + w * 512;
    g2l16(tb, tl);
    g2l16(tb + 256, tl + 256);
  }
  __syncthreads();

  int jw = w * 256;   // wave's private j range [jw, jw+256)
  const f32x4* b24 = (const f32x4*)b2;
  f32x4 b0 = b24[pl], b1v = b24[8 + pl];
  size_t ibase = (size_t)i * (LSEQ * PD);

  // lane loads s rows c = q+8m, j-cols [j0 + pl*4, +4)
  auto SLOAD = [&](int ck, f32x4* sr) {
    const float* b = sT + (size_t)q * LSEQ + (jw + ck * 32) + pl * 4;
    #pragma unroll
    for (int m = 0; m < 4; ++m)
      sr[m] = *(const f32x4*)(b + (size_t)(8 * m) * LSEQ);
  };
  // linear slot write: flat f32x4 idx m*64+lane (conflict-free)
  auto SWRITE = [&](f32x4* sr, float* slot) {
    #pragma unroll
    for (int m = 0; m < 4; ++m)
      ((f32x4*)slot)[m * 64 + lane] = sr[m];
  };
  auto PLOAD = [&](int ck, f32x4* pf) {
    const f32x4* pp = (const f32x4*)(pair + ibase + (size_t)(jw + ck * 32 + q * 4) * PD);
    #pragma unroll
    for (int jj = 0; jj < 4; ++jj) {
      pf[jj * 2]     = __builtin_nontemporal_load(&pp[jj * 16 + pl]);
      pf[jj * 2 + 1] = __builtin_nontemporal_load(&pp[jj * 16 + 8 + pl]);
    }
  };
  // accumulate into pf in place, then store
  auto COMPUTE_STORE = [&](int ck, f32x4* pf, const float* slot) {
    #pragma unroll
    for (int jj = 0; jj < 4; ++jj) { pf[jj * 2] += b0; pf[jj * 2 + 1] += b1v; }
    const f32x4* t4 = (const f32x4*)t_lds;
    const f32x4* s4 = (const f32x4*)slot;
    #pragma unroll 8
    for (int c = 0; c < DM; ++c) {
      f32x4 t0 = t4[c * 16 + pl];
      f32x4 t1 = t4[c * 16 + 8 + pl];
      // slot flat idx for (c, col=q): (c>>3)*64 + (c&7)*8 + q  (broadcast read)
      f32x4 sA = s4[((c >> 3) << 6) + ((c & 7) << 3) + q];
      fma4(pf[0], sA.x, t0); fma4(pf[1], sA.x, t1);
      fma4(pf[2], sA.y, t0); fma4(pf[3], sA.y, t1);
      fma4(pf[4], sA.z, t0); fma4(pf[5], sA.z, t1);
      fma4(pf[6], sA.w, t0); fma4(pf[7], sA.w, t1);
    }
    f32x4* po = (f32x4*)(out + ibase + (size_t)(jw + ck * 32 + q * 4) * PD);
    #pragma unroll
    for (int jj = 0; jj < 4; ++jj) {
      __builtin_nontemporal_store(pf[jj * 2],     &po[jj * 16 + pl]);
      __builtin_nontemporal_store(pf[jj * 2 + 1], &po[jj * 16 + 8 + pl]);
    }
  };

  f32x4 srA[4], srB[4], pfA[8], pfB[8];
  float* slotA = &s_slot[w][0][0];
  float* slotB = &s_slot[w][1][0];

  SLOAD(0, srA);
  PLOAD(0, pfA);

  #pragma unroll 1
  for (int k4 = 0; k4 < 4; ++k4) {
    int ck = k4 * 2;
    SWRITE(srA, slotA);                 // waits vmcnt for srA (landed last iter)
    SLOAD(ck + 1, srB);                 // issue next chunk's reads
    PLOAD(ck + 1, pfB);
    __builtin_amdgcn_sched_barrier(0);
    COMPUTE_STORE(ck, pfA, slotA);      // LDS reads + FMA + nt stores

    SWRITE(srB, slotB);
    if (k4 < 3) { SLOAD(ck + 2, srA); PLOAD(ck + 2, pfA); }
    __builtin_amdgcn_sched_barrier(0);
    COMPUTE_STORE(ck + 1, pfB, slotB);
  }
}

// Fallback (ws too small for t): single-tile kernel computing t in-block.
__global__ __launch_bounds__(256) void k_main_fb(const float* __restrict__ sT,
    const float* __restrict__ W2, const float* __restrict__ b2,
    const float* __restrict__ pair, float* __restrict__ out) {
  __shared__ float t_lds[DM][PD];
  __shared__ float s_lds[DM][128];
  __shared__ float sish[DM];
  int tid = threadIdx.x;
  int bid = ((blockIdx.x & 7) << 10) + (blockIdx.x >> 3);
  int i = bid >> 3;
  int jt = (bid & 7) * 128;
  int pl = tid & 7, jg = tid >> 3;
  if (tid < DM) sish[tid] = sT[tid * LSEQ + i];
  __syncthreads();
  {
    int p = tid & 63, c0 = tid >> 6;
    #pragma unroll
    for (int k = 0; k < 8; ++k) {
      int c = c0 * 8 + k;
      float acc = 0.f;
      #pragma unroll
      for (int d = 0; d < DM; ++d)
        acc = fmaf(sish[d], W2[(c * DM + d) * PD + p], acc);
      t_lds[c][p] = acc;
    }
  }
  #pragma unroll
  for (int k = 0; k < 2; ++k) {
    int idx = k * 256 + tid;
    int c = idx >> 5, j4 = idx & 31;
    ((f32x4*)&s_lds[0][0])[idx] =
        ((const f32x4*)(sT + (size_t)c * LSEQ + jt))[j4];
  }
  __syncthreads();
  size_t rowbase = (size_t)i * (LSEQ * PD) + (size_t)(jt + jg * 4) * PD;
  const f32x4* pp = (const f32x4*)(pair + rowbase);
  f32x4 acc0[4], acc1[4];
  #pragma unroll
  for (int jj = 0; jj < 4; ++jj) {
    acc0[jj] = pp[jj * 16 + pl];
    acc1[jj] = pp[jj * 16 + 8 + pl];
  }
  const f32x4* t4 = (const f32x4*)&t_lds[0][0];
  const f32x4* s4 = (const f32x4*)&s_lds[0][0];
  #pragma unroll 8
  for (int c = 0; c < DM; ++c) {
    f32x4 t0 = t4[c * 16 + pl];
    f32x4 t1 = t4[c * 16 + 8 + pl];
    f32x4 sA = s4[c * 32 + jg];
    fma4(acc0[0], sA.x, t0); fma4(acc1[0], sA.x, t1);
    fma4(acc0[1], sA.y, t0); fma4(acc1[1], sA.y, t1);
    fma4(acc0[2], sA.z, t0); fma4(acc1[2], sA.z, t1);
    fma4(acc0[3], sA.w, t0); fma4(acc1[3], sA.w, t1);
  }
  const f32x4* b24 = (const f32x4*)b2;
  f32x4 b0 = b24[pl], b1v = b24[8 + pl];
  f32x4* po = (f32x4*)(out + rowbase);
  #pragma unroll
  for (int jj = 0; jj < 4; ++jj) {
    po[jj * 16 + pl] = acc0[jj] + b0;
    po[jj * 16 + 8 + pl] = acc1[jj] + b1v;
  }
}

extern "C" void kernel_launch(void* const* d_in, const int* in_sizes, int n_in,
                              void* d_out, int out_size, void* d_ws, size_t ws_size,
                              hipStream_t stream) {
  const float* seq  = (const float*)d_in[0];
  const float* pair = (const float*)d_in[1];
  const float* W1   = (const float*)d_in[2];
  const float* b1   = (const float*)d_in[3];
  const float* W2   = (const float*)d_in[4];
  const float* b2   = (const float*)d_in[5];
  float* out = (float*)d_out;
  float* ws  = (float*)d_ws;

  float* sT = ws;                       // 32*1024 floats (128 KB)
  float* t  = ws + DM * LSEQ;           // 1024*32*64 floats (8 MB)
  size_t need = (size_t)(DM * LSEQ + (size_t)LSEQ * DM * PD) * sizeof(float);

  if (ws_size >= need) {
    k_prep<true><<<LSEQ / 4, 256, 0, stream>>>(seq, W1, b1, W2, sT, t);
    k_mainw<<<LSEQ, 256, 0, stream>>>(sT, t, b2, pair, out);
  } else {
    k_prep<false><<<LSEQ / 4, 256, 0, stream>>>(seq, W1, b1, W2, sT, nullptr);
    k_main_fb<<<LSEQ * 8, 256, 0, stream>>>(sT, W2, b2, pair, out);
  }
}